// Round 11
// baseline (398.294 us; speedup 1.0000x reference)
//
#include <hip/hip_runtime.h>
#include <hip/hip_fp16.h>
#include <math.h>

#define BATCH 2048
#define NBAS 103
#define NPAIR 102     // pair-rows per input feature: (r, r+1), r in [0,101]
#define OUTR 243      // real output width of hidden layers
#define OUTP 256      // padded output width

typedef _Float16 half2v __attribute__((ext_vector_type(2)));

__device__ __forceinline__ float dot2(unsigned a, unsigned b, float c) {
#if __has_builtin(__builtin_amdgcn_fdot2)
    return __builtin_amdgcn_fdot2(__builtin_bit_cast(half2v, a),
                                  __builtin_bit_cast(half2v, b), c, false);
#else
    __half2 ha = __builtin_bit_cast(__half2, a), hb = __builtin_bit_cast(__half2, b);
    c = fmaf(__low2float(ha), __low2float(hb), c);
    c = fmaf(__high2float(ha), __high2float(hb), c);
    return c;
#endif
}

// ---------------- shared spline-eval: (x, i) -> meta {half2 w01, half2 w23, pairoff, flat}
// u = (x+0.56)/0.02. Interval j=floor(u); nonzero basis n=j-3..j clipped to [0,102].
// m.z = (i*NPAIR + idxc) << 8 : pair-row offset in the table layout pairT[i][r][256].
__device__ __forceinline__ uint4 make_meta(float x, int i) {
    float u = (x + 0.56f) * 50.0f;
    bool inr = (u >= 0.0f) && (u < 106.0f);
    float fj = floorf(u);
    float t = u - fj;
    int j = (int)fj;
    j = j < -1 ? -1 : (j > 106 ? 106 : j);
    float omt = 1.0f - t;
    float t2 = t * t, t3 = t2 * t;
    float w[4];
    w[0] = omt * omt * omt * (1.0f / 6.0f);
    w[1] = (3.0f * t3 - 6.0f * t2 + 4.0f) * (1.0f / 6.0f);
    w[2] = (-3.0f * t3 + 3.0f * t2 + 3.0f * t + 1.0f) * (1.0f / 6.0f);
    w[3] = t3 * (1.0f / 6.0f);
    int idx = j - 3;                       // first basis index n
    int idxc = idx < 0 ? 0 : (idx > 99 ? 99 : idx);   // clamp so idxc+3 <= 102
    int d = idx - idxc;                    // nonzero only at edges
    float wc[4];
    #pragma unroll
    for (int m = 0; m < 4; ++m) {          // weight for row idxc+m is w[(idxc+m)-idx]
        int s = m - d;
        wc[m] = (inr && s >= 0 && s < 4) ? w[s] : 0.0f;
    }
    __half2 w01 = __floats2half2_rn(wc[0], wc[1]);
    __half2 w23 = __floats2half2_rn(wc[2], wc[3]);
    uint4 m4;
    m4.x = __builtin_bit_cast(unsigned, w01);
    m4.y = __builtin_bit_cast(unsigned, w23);
    m4.z = (unsigned)((i * NPAIR + idxc) << 8);   // pair-row offset in half2/uint units
    m4.w = (unsigned)(i * NBAS + idxc);           // flat index for fp32 final layer
    return m4;
}

// ---------------- pair-table build: sw[o][i][n] (fp32) -> pairT[i][r][o] = half2(v_r,v_r+1)
// R1-EXACT 32-row-tile body (measured best). Block = (feature i, 32-o-tile).
// Phase 1: each wave loads 8 rows (16 independent coalesced 256B loads) into
// tile[32][106] (53-dword stride, gcd(53,32)=1 -> conflict-free column reads).
// Phase 2: packed half2 writes, 128B contiguous per 32-lane group.
// R5/R9 lesson: 64-row/contiguous-write variant is SLOWER (occupancy & latency exposure).
__device__ __forceinline__ void pairgen_body(
    const float* __restrict__ sw, int IN, unsigned* __restrict__ pairT,
    __half (*tile)[106], int i, int obase)
{
    int nl = threadIdx.x & 63;
    int w = threadIdx.x >> 6;
    #pragma unroll
    for (int k = 0; k < 8; ++k) {
        int r = w * 8 + k;                 // local row 0..31
        int o = obase + r;
        if (o < OUTR) {
            const float* p = sw + ((size_t)o * IN + i) * NBAS;
            tile[r][nl] = __float2half(p[nl]);                        // n = 0..63
            if (nl + 64 < NBAS)                                        // n = 64..102 ONLY
                tile[r][nl + 64] = __float2half(p[nl + 64]);
        }
    }
    __syncthreads();
    unsigned* dst = pairT + (size_t)i * NPAIR * 256 + obase;
    for (int idx = threadIdx.x; idx < NPAIR * 32; idx += 256) {
        int p = idx >> 5, o = idx & 31;    // pair-row, local o
        unsigned v = 0;
        if (obase + o < OUTR) {
            unsigned lo = __half_as_ushort(tile[o][p]);
            unsigned hi = __half_as_ushort(tile[o][p + 1]);
            v = lo | (hi << 16);
        }
        dst[(size_t)p * 256 + o] = v;
    }
}

// standalone pairgen (atomic fallback path): grid (IN, 8)
__global__ __launch_bounds__(256) void pairgen_kernel(
    const float* __restrict__ sw, int IN, unsigned* __restrict__ pairT)
{
    __shared__ __half tile[32][106];       // 6,784 B
    pairgen_body(sw, IN, pairT, tile, blockIdx.x, blockIdx.y * 32);
}

// ---------------- FRONT: pg0 + pg1 + layer-0 basis in one dispatch ------------------------
// pg1 depends only on sw[1] -- hoisting it here takes it off the serial path (R10 paid
// ~40 us for fused_pg_bm[1]; now layer 1 needs only a ~10 us basis_mid). pg0 -> T0small
// (separate 6.7 MB), pg1 -> the SHARED 25 MB table recycled by layers 1..4.
// Flat grid 2968: [0,512) pg0 (i=bx>>3, ot=bx&7); [512,2456) pg1 (i=t>>3, ot=t&7);
// [2456,2968) basis0 (512 x 256 = BATCH*64 exact).
__global__ __launch_bounds__(256) void front_kernel(
    const float* __restrict__ sw0, unsigned* __restrict__ pT0,
    const float* __restrict__ sw1, unsigned* __restrict__ pT1,
    const float* __restrict__ xin, uint4* __restrict__ meta)
{
    int bx = blockIdx.x;
    if (bx < 2456) {
        __shared__ __half tile[32][106];
        if (bx < 512)
            pairgen_body(sw0, 64, pT0, tile, bx >> 3, (bx & 7) * 32);
        else {
            int t = bx - 512;
            pairgen_body(sw1, OUTR, pT1, tile, t >> 3, (t & 7) * 32);
        }
    } else {
        int e = (bx - 2456) * 256 + threadIdx.x;   // < 131072 = BATCH*64 exactly
        int b = e >> 6, i = e & 63;
        meta[e] = make_meta(xin[(size_t)b * 64 + i], i);
    }
}

// ---------------- basis from a plain activation buffer (+ optional fused zeroing; fallback) --
template <int IN>
__global__ __launch_bounds__(256) void basis_kernel(
    const float* __restrict__ xin, int xstride, uint4* __restrict__ meta,
    float4* __restrict__ zbuf)     // if non-null: first 131072 threads zero 2 MB
{
    int e = blockIdx.x * 256 + threadIdx.x;
    if (zbuf && e < (BATCH * OUTP) / 4) zbuf[e] = make_float4(0.f, 0.f, 0.f, 0.f);
    if (e >= BATCH * IN) return;
    int b = e / IN, i = e - b * IN;
    meta[e] = make_meta(xin[(size_t)b * xstride + i], i);
}

// ---------------- basis + 8-way partial reduction + residual ----------------
template <bool ADDRES>
__global__ __launch_bounds__(256) void basis_mid_kernel(
    const float* __restrict__ hprev,        // stride OUTP (unused if !ADDRES)
    const float* __restrict__ parts,        // 8 buffers of BATCH*OUTP floats
    uint4* __restrict__ meta, float* __restrict__ hcomb)
{
    int e = blockIdx.x * 256 + threadIdx.x;
    if (e >= BATCH * OUTR) return;
    int b = e / OUTR, i = e - b * OUTR;
    size_t addr = (size_t)b * OUTP + i;
    const size_t PS = (size_t)BATCH * OUTP;
    float h = ADDRES ? hprev[addr] : 0.0f;
    #pragma unroll
    for (int s = 0; s < 8; ++s) h += parts[s * PS + addr];
    hcomb[addr] = h;
    meta[e] = make_meta(h, i);
}

// ---------------- FUSED: pairgen[l] + basis_mid[l] (layers 2..4 workhorse) ----------------
// pg[l] depends only on sw[l]; bm[l] only on layer_store[l-1]'s parts -> co-scheduled.
// Single shared pairT recycled every layer (addresses stay L2/L3-warm; R8's 5 separate
// tables regressed 429 vs 400). grid (1944, 2): y==0 -> pg (i=bx>>3, ot=bx&7);
// y==1 -> bm (e = bx*256+tid covers BATCH*OUTR exactly).
template <bool ADDRES>
__global__ __launch_bounds__(256) void fused_pg_bm_kernel(
    const float* __restrict__ sw, unsigned* __restrict__ pairT,
    const float* __restrict__ hprev, const float* __restrict__ parts,
    uint4* __restrict__ meta, float* __restrict__ hcomb)
{
    if (blockIdx.y == 0) {
        __shared__ __half tile[32][106];
        pairgen_body(sw, OUTR, pairT, tile, blockIdx.x >> 3, (blockIdx.x & 7) * 32);
    } else {
        int e = blockIdx.x * 256 + threadIdx.x;
        if (e >= BATCH * OUTR) return;
        int b = e / OUTR, i = e - b * OUTR;
        size_t addr = (size_t)b * OUTP + i;
        const size_t PS = (size_t)BATCH * OUTP;
        float h = ADDRES ? hprev[addr] : 0.0f;
        #pragma unroll
        for (int s = 0; s < 8; ++s) h += parts[s * PS + addr];
        hcomb[addr] = h;
        meta[e] = make_meta(h, i);
    }
}

// ---------------- FUSED layer-0 front (mid-ws fallback) ----------
__global__ __launch_bounds__(256) void fused0_kernel(
    const float* __restrict__ sw0, unsigned* __restrict__ pairT,
    const float* __restrict__ xin, uint4* __restrict__ meta)
{
    if (blockIdx.y == 0) {
        __shared__ __half tile[32][106];
        pairgen_body(sw0, 64, pairT, tile, blockIdx.x >> 3, (blockIdx.x & 7) * 32);
    } else {
        int e = blockIdx.x * 256 + threadIdx.x;   // < 131072 = BATCH*64 exactly
        int b = e >> 6, i = e & 63;
        meta[e] = make_meta(xin[(size_t)b * 64 + i], i);
    }
}

// ---------------- layer kernel: XCD-pinned gather, 2 batch rows/wave, 2-i pipeline --------
// Block = 256 threads (4 waves); wave handles TWO batch rows, lane covers o = lane*4..+3.
// grid = (8, BATCH/8): blockIdx.x = i-slice pinned to one XCD (its ~3.2 MB of pairT in L2).
// wave is readfirstlane-uniform -> meta loads compile to s_load via K$ (R0->R1 win).
// R11: EXPLICIT 2-i UNROLL. At ~40 B/cy/CU the kernel was MLP-limited (4 outstanding
// 16-B gathers/wave can hide only ~50cy of ~200cy L2 latency). Issuing 8 independent
// gathers (i and i+1) before the first dot2 doubles bytes-in-flight. Meta stays in
// SGPRs; 8 uint4 in flight ~ 50-60 VGPR, under the 64-cap for 8 waves/SIMD.
// NOTE: nt loads (R2) demote L2 LRU -- net regression; don't.
template <int IN>
__global__ __launch_bounds__(256, 8) void layer_store_kernel(
    const unsigned* __restrict__ pairT, const uint4* __restrict__ meta,
    const float* __restrict__ h_in, int hstride,
    const float* __restrict__ bw,
    const float* __restrict__ wbp, const float* __restrict__ wsp,
    float* __restrict__ part)
{
    const int lane = threadIdx.x & 63;
    const int wave = __builtin_amdgcn_readfirstlane(threadIdx.x >> 6);
    const int b0 = blockIdx.y * 8 + wave * 2;
    const int cx = blockIdx.x;             // i-slice = XCD id
    const int i0 = (IN * cx) >> 3;
    const int i1 = (IN * (cx + 1)) >> 3;
    const uint4* mp0 = meta + (size_t)b0 * IN;
    const uint4* mp1 = mp0 + IN;
    float a0[4] = {0.f, 0.f, 0.f, 0.f};
    float a1[4] = {0.f, 0.f, 0.f, 0.f};
    int i = i0;
    for (; i + 1 < i1; i += 2) {
        uint4 m0 = mp0[i];                             // wave-uniform -> s_load
        uint4 m1 = mp1[i];
        uint4 n0 = mp0[i + 1];
        uint4 n1 = mp1[i + 1];
        const uint4* pA = (const uint4*)(pairT + m0.z) + lane;
        const uint4* pB = (const uint4*)(pairT + m1.z) + lane;
        const uint4* qA = (const uint4*)(pairT + n0.z) + lane;
        const uint4* qB = (const uint4*)(pairT + n1.z) + lane;
        uint4 ra = pA[0];                              // 8 independent 16-B gathers
        uint4 rb = pA[128];
        uint4 rc = pB[0];
        uint4 rd = pB[128];
        uint4 sa = qA[0];
        uint4 sb = qA[128];
        uint4 sc = qB[0];
        uint4 sd = qB[128];
        a0[0] = dot2(m0.x, ra.x, a0[0]); a0[1] = dot2(m0.x, ra.y, a0[1]);
        a0[2] = dot2(m0.x, ra.z, a0[2]); a0[3] = dot2(m0.x, ra.w, a0[3]);
        a0[0] = dot2(m0.y, rb.x, a0[0]); a0[1] = dot2(m0.y, rb.y, a0[1]);
        a0[2] = dot2(m0.y, rb.z, a0[2]); a0[3] = dot2(m0.y, rb.w, a0[3]);
        a1[0] = dot2(m1.x, rc.x, a1[0]); a1[1] = dot2(m1.x, rc.y, a1[1]);
        a1[2] = dot2(m1.x, rc.z, a1[2]); a1[3] = dot2(m1.x, rc.w, a1[3]);
        a1[0] = dot2(m1.y, rd.x, a1[0]); a1[1] = dot2(m1.y, rd.y, a1[1]);
        a1[2] = dot2(m1.y, rd.z, a1[2]); a1[3] = dot2(m1.y, rd.w, a1[3]);
        a0[0] = dot2(n0.x, sa.x, a0[0]); a0[1] = dot2(n0.x, sa.y, a0[1]);
        a0[2] = dot2(n0.x, sa.z, a0[2]); a0[3] = dot2(n0.x, sa.w, a0[3]);
        a0[0] = dot2(n0.y, sb.x, a0[0]); a0[1] = dot2(n0.y, sb.y, a0[1]);
        a0[2] = dot2(n0.y, sb.z, a0[2]); a0[3] = dot2(n0.y, sb.w, a0[3]);
        a1[0] = dot2(n1.x, sc.x, a1[0]); a1[1] = dot2(n1.x, sc.y, a1[1]);
        a1[2] = dot2(n1.x, sc.z, a1[2]); a1[3] = dot2(n1.x, sc.w, a1[3]);
        a1[0] = dot2(n1.y, sd.x, a1[0]); a1[1] = dot2(n1.y, sd.y, a1[1]);
        a1[2] = dot2(n1.y, sd.z, a1[2]); a1[3] = dot2(n1.y, sd.w, a1[3]);
    }
    if (i < i1) {                          // odd-count tail (IN=243 slices are 30 or 31)
        uint4 m0 = mp0[i];
        uint4 m1 = mp1[i];
        const uint4* pA = (const uint4*)(pairT + m0.z) + lane;
        const uint4* pB = (const uint4*)(pairT + m1.z) + lane;
        uint4 ra = pA[0];
        uint4 rb = pA[128];
        uint4 rc = pB[0];
        uint4 rd = pB[128];
        a0[0] = dot2(m0.x, ra.x, a0[0]); a0[1] = dot2(m0.x, ra.y, a0[1]);
        a0[2] = dot2(m0.x, ra.z, a0[2]); a0[3] = dot2(m0.x, ra.w, a0[3]);
        a0[0] = dot2(m0.y, rb.x, a0[0]); a0[1] = dot2(m0.y, rb.y, a0[1]);
        a0[2] = dot2(m0.y, rb.z, a0[2]); a0[3] = dot2(m0.y, rb.w, a0[3]);
        a1[0] = dot2(m1.x, rc.x, a1[0]); a1[1] = dot2(m1.x, rc.y, a1[1]);
        a1[2] = dot2(m1.x, rc.z, a1[2]); a1[3] = dot2(m1.x, rc.w, a1[3]);
        a1[0] = dot2(m1.y, rd.x, a1[0]); a1[1] = dot2(m1.y, rd.y, a1[1]);
        a1[2] = dot2(m1.y, rd.z, a1[2]); a1[3] = dot2(m1.y, rd.w, a1[3]);
    }
    float wsv = wsp[0];
    float wbv = wbp[0];
    float4 v0 = make_float4(wsv * a0[0], wsv * a0[1], wsv * a0[2], wsv * a0[3]);
    float4 v1 = make_float4(wsv * a1[0], wsv * a1[1], wsv * a1[2], wsv * a1[3]);
    if (wbv != 0.0f) {                     // base path: never taken for given inputs (wb==0)
        float* pv0 = &v0.x; float* pv1 = &v1.x;
        for (int c = 0; c < 4; ++c) {
            int o = lane * 4 + c;
            if (o < OUTR) {
                float bs0 = 0.0f, bs1 = 0.0f;
                for (int k = i0; k < i1; ++k) {
                    float x0 = h_in[(size_t)b0 * hstride + k];
                    float x1 = h_in[(size_t)(b0 + 1) * hstride + k];
                    bs0 = fmaf(x0 / (1.0f + expf(-x0)), bw[o * IN + k], bs0);
                    bs1 = fmaf(x1 / (1.0f + expf(-x1)), bw[o * IN + k], bs1);
                }
                pv0[c] += wbv * bs0;
                pv1[c] += wbv * bs1;
            }
        }
    }
    float* d0 = part + ((size_t)cx * BATCH + b0) * OUTP + lane * 4;
    *(float4*)d0 = v0;
    *(float4*)(d0 + OUTP) = v1;
}

// ---------------- FALLBACK layer kernel (atomic version, needs only 37.5 MB ws) ----------
template <int IN, bool RES>
__global__ __launch_bounds__(256, 8) void layer_atomic_kernel(
    const unsigned* __restrict__ pairT, const uint4* __restrict__ meta,
    const float* __restrict__ h_in, int hstride,
    const float* __restrict__ bw,
    const float* __restrict__ wbp, const float* __restrict__ wsp,
    float* __restrict__ out)
{
    const int lane = threadIdx.x & 63;
    const int wave = __builtin_amdgcn_readfirstlane(threadIdx.x >> 6);
    const int b = blockIdx.y * 4 + wave;
    const int cx = blockIdx.x;
    const int i0 = (IN * cx) >> 3;
    const int i1 = (IN * (cx + 1)) >> 3;
    const uint4* mp = meta + (size_t)b * IN;
    float acc[4] = {0.f, 0.f, 0.f, 0.f};
    #pragma unroll 2
    for (int i = i0; i < i1; ++i) {
        uint4 m = mp[i];
        const uint4* pA = (const uint4*)(pairT + m.z) + lane;
        uint4 ra = pA[0];
        uint4 rb = pA[128];
        acc[0] = dot2(m.x, ra.x, acc[0]); acc[1] = dot2(m.x, ra.y, acc[1]);
        acc[2] = dot2(m.x, ra.z, acc[2]); acc[3] = dot2(m.x, ra.w, acc[3]);
        acc[0] = dot2(m.y, rb.x, acc[0]); acc[1] = dot2(m.y, rb.y, acc[1]);
        acc[2] = dot2(m.y, rb.z, acc[2]); acc[3] = dot2(m.y, rb.w, acc[3]);
    }
    float wsv = wsp[0];
    float wbv = wbp[0];
    #pragma unroll
    for (int c = 0; c < 4; ++c) {
        int o = lane * 4 + c;
        float v = wsv * acc[c];
        if (RES && cx == 0) v += h_in[(size_t)b * hstride + o];
        if (wbv != 0.0f && o < OUTR) {
            float bs = 0.0f;
            for (int i = i0; i < i1; ++i) {
                float xx = h_in[(size_t)b * hstride + i];
                bs = fmaf(xx / (1.0f + expf(-xx)), bw[o * IN + i], bs);
            }
            v += wbv * bs;
        }
        unsafeAtomicAdd(&out[(size_t)b * OUTP + o], v);
    }
}

// ---------------- FUSED tail: h5 = h4 + sum(parts) inline + final 243 -> 1 ----------------
__global__ __launch_bounds__(256) void final_fused_kernel(
    const float* __restrict__ sw5,          // (243*103,) original fp32 layout
    const float* __restrict__ hprev,        // h4, stride OUTP
    const float* __restrict__ parts,        // 8 buffers of BATCH*OUTP floats
    const float* __restrict__ bw5,
    const float* __restrict__ wbp, const float* __restrict__ wsp,
    float* __restrict__ out)
{
    int wave = threadIdx.x >> 6, lane = threadIdx.x & 63;
    int b = blockIdx.x * 4 + wave;
    const size_t PS = (size_t)BATCH * OUTP;
    float s = 0.0f, bs = 0.0f;
    for (int i = lane; i < OUTR; i += 64) {
        size_t addr = (size_t)b * OUTP + i;
        float h = hprev[addr];
        #pragma unroll
        for (int ss = 0; ss < 8; ++ss) h += parts[ss * PS + addr];
        uint4 m = make_meta(h, i);
        __half2 w01 = __builtin_bit_cast(__half2, m.x);
        __half2 w23 = __builtin_bit_cast(__half2, m.y);
        const float* p = sw5 + m.w;
        s += __low2float(w01) * p[0] + __high2float(w01) * p[1]
           + __low2float(w23) * p[2] + __high2float(w23) * p[3];
        bs = fmaf(h / (1.0f + expf(-h)), bw5[i], bs);   // base path partial (wb==0 typ.)
    }
    #pragma unroll
    for (int d = 32; d; d >>= 1) {
        s += __shfl_down(s, d, 64);
        bs += __shfl_down(bs, d, 64);
    }
    if (lane == 0) out[b] = wsp[0] * s + wbp[0] * bs;
}

// ---------------- final layer 243 -> 1 (atomic fallback path) ----------------
__global__ __launch_bounds__(256) void final_kernel(
    const float* __restrict__ sw5,
    const uint4* __restrict__ meta,
    const float* __restrict__ h, const float* __restrict__ bw5,
    const float* __restrict__ wbp, const float* __restrict__ wsp,
    float* __restrict__ out)
{
    int wave = threadIdx.x >> 6, lane = threadIdx.x & 63;
    int b = blockIdx.x * 4 + wave;
    float s = 0.0f;
    for (int i = lane; i < OUTR; i += 64) {
        uint4 m = meta[(size_t)b * OUTR + i];
        __half2 w01 = __builtin_bit_cast(__half2, m.x);
        __half2 w23 = __builtin_bit_cast(__half2, m.y);
        const float* p = sw5 + m.w;
        s += __low2float(w01) * p[0] + __high2float(w01) * p[1]
           + __low2float(w23) * p[2] + __high2float(w23) * p[3];
    }
    #pragma unroll
    for (int d = 32; d; d >>= 1) s += __shfl_down(s, d, 64);
    if (lane == 0) {
        float v = wsp[0] * s;
        float wbv = wbp[0];
        if (wbv != 0.0f) {
            float bs = 0.0f;
            for (int i = 0; i < OUTR; ++i) {
                float xx = h[(size_t)b * OUTP + i];
                bs = fmaf(xx / (1.0f + expf(-xx)), bw5[i], bs);
            }
            v += wbv * bs;
        }
        out[b] = v;
    }
}

extern "C" void kernel_launch(void* const* d_in, const int* in_sizes, int n_in,
                              void* d_out, int out_size, void* d_ws, size_t ws_size,
                              hipStream_t stream)
{
    const float* x = (const float*)d_in[0];
    const float *bw[6], *sw[6], *wb[6], *ws[6];
    for (int l = 0; l < 6; ++l) {
        bw[l] = (const float*)d_in[1 + 4 * l];
        sw[l] = (const float*)d_in[2 + 4 * l];
        wb[l] = (const float*)d_in[3 + 4 * l];
        ws[l] = (const float*)d_in[4 + 4 * l];
    }
    char* base = (char*)d_ws;
    float* outp = (float*)d_out;
    const int NB243 = (BATCH * OUTR + 255) / 256;

    const size_t NEED_FRONT = 60999680;      // primary path (+6.7 MB T0small)
    const size_t NEED_MID = 54315008;        // R10 path (single shared table)
    const size_t NEED_ATM = 37537792;        // atomic fallback

    // ---- common workspace map ----
    // pairT1 :          0 .. 25,380,864   (243*102*256*4) -- shared, recycled (L2/L3-warm)
    // meta   : 25,380,864 .. 33,343,488   (2048*243*16)
    // parts  : 33,343,488 .. 50,120,704   (8 * 2 MB)
    // hcA    : 50,120,704 .. 52,217,856
    // hcB    : 52,217,856 .. 54,315,008
    // T0     : 54,315,008 .. 60,999,680   (64*102*256*4, primary only)
    unsigned* pairT1 = (unsigned*)(base + 0);
    uint4*    meta   = (uint4*)(base + 25380864);

    if (ws_size >= NEED_FRONT) {
        float*    parts = (float*)(base + 33343488);
        float*    hcA   = (float*)(base + 50120704);
        float*    hcB   = (float*)(base + 52217856);
        unsigned* T0    = (unsigned*)(base + 54315008);

        // front: pg0 -> T0, pg1 -> shared pairT1, basis0 (2968 blocks)
        front_kernel<<<2968, 256, 0, stream>>>(sw[0], T0, sw[1], pairT1, x, meta);

        layer_store_kernel<64><<<dim3(8, BATCH / 8), 256, 0, stream>>>(
            T0, meta, x, 64, bw[0], wb[0], ws[0], parts);

        float* hin = hcA; float* hout = hcB;   // hin = h_l carrier
        for (int l = 1; l <= 4; ++l) {
            if (l == 1)        // T1 already built by front -> bm only (~10 us vs ~40)
                basis_mid_kernel<false><<<NB243, 256, 0, stream>>>(nullptr, parts, meta, hin);
            else
                fused_pg_bm_kernel<true><<<dim3(1944, 2), 256, 0, stream>>>(
                    sw[l], pairT1, hout, parts, meta, hin);
            layer_store_kernel<243><<<dim3(8, BATCH / 8), 256, 0, stream>>>(
                pairT1, meta, hin, OUTP, bw[l], wb[l], ws[l], parts);
            float* tmp = hin; hin = hout; hout = tmp;   // hout now holds h_l
        }
        // fused tail: h5 = h4 + sum(parts of layer 4) inline; h4 is in hout
        final_fused_kernel<<<BATCH / 4, 256, 0, stream>>>(
            sw[5], hout, parts, bw[5], wb[5], ws[5], outp);
    } else if (ws_size >= NEED_MID) {
        // ---- R10 path (proven 397 us) ----
        float* parts = (float*)(base + 33343488);
        float* hcA   = (float*)(base + 50120704);
        float* hcB   = (float*)(base + 52217856);

        fused0_kernel<<<dim3(512, 2), 256, 0, stream>>>(sw[0], pairT1, x, meta);
        layer_store_kernel<64><<<dim3(8, BATCH / 8), 256, 0, stream>>>(
            pairT1, meta, x, 64, bw[0], wb[0], ws[0], parts);

        float* hin = hcA; float* hout = hcB;
        for (int l = 1; l <= 4; ++l) {
            if (l == 1)
                fused_pg_bm_kernel<false><<<dim3(1944, 2), 256, 0, stream>>>(
                    sw[l], pairT1, nullptr, parts, meta, hin);
            else
                fused_pg_bm_kernel<true><<<dim3(1944, 2), 256, 0, stream>>>(
                    sw[l], pairT1, hout, parts, meta, hin);
            layer_store_kernel<243><<<dim3(8, BATCH / 8), 256, 0, stream>>>(
                pairT1, meta, hin, OUTP, bw[l], wb[l], ws[l], parts);
            float* tmp = hin; hin = hout; hout = tmp;
        }
        final_fused_kernel<<<BATCH / 4, 256, 0, stream>>>(
            sw[5], hout, parts, bw[5], wb[5], ws[5], outp);
    } else {
        // ---- fallback: proven atomic path, needs 37,537,792 B ----
        if (ws_size < NEED_ATM) return;
        float* hA = (float*)(base + 33343488);
        float* hB = (float*)(base + 35440640);
        pairgen_kernel<<<dim3(64, 8), 256, 0, stream>>>(sw[0], 64, pairT1);
        basis_kernel<64><<<(BATCH * 64) / 256, 256, 0, stream>>>(x, 64, meta, (float4*)hA);
        layer_atomic_kernel<64, false><<<dim3(8, BATCH / 4), 256, 0, stream>>>(
            pairT1, meta, x, 64, bw[0], wb[0], ws[0], hA);
        float* hin = hA; float* hout = hB;
        for (int l = 1; l <= 4; ++l) {
            pairgen_kernel<<<dim3(OUTR, 8), 256, 0, stream>>>(sw[l], OUTR, pairT1);
            basis_kernel<243><<<NB243, 256, 0, stream>>>(hin, OUTP, meta, (float4*)hout);
            layer_atomic_kernel<243, true><<<dim3(8, BATCH / 4), 256, 0, stream>>>(
                pairT1, meta, hin, OUTP, bw[l], wb[l], ws[l], hout);
            float* tmp = hin; hin = hout; hout = tmp;
        }
        basis_kernel<243><<<NB243, 256, 0, stream>>>(hin, OUTP, meta, nullptr);
        final_kernel<<<BATCH / 4, 256, 0, stream>>>(sw[5], meta, hin, bw[5], wb[5], ws[5], outp);
    }
}